// Round 7
// baseline (691.736 us; speedup 1.0000x reference)
//
#include <hip/hip_runtime.h>

// ---------------------------------------------------------------------------
// DNANet round 6: strip-parallel segmented attention + register-stationary
// projections. N=50000, E=600000 (+N self loops), HID=64, HEADS=4, d=16.
//
// Edge list sorted by dst (CSR scatter). Attention: each 16-lane group owns a
// fixed strip of SEDGE edges; lane holds dims 4*(gl)..4*gl+3; head = gl>>2
// (4 lanes). Per-edge: 3 uint4 gathers of packed bf16 (k|v<<16), 12 QK FMAs,
// 2-step shfl_xor head reduce, softmax over L, 12 weighted FMAs. Segment
// flush = 4 atomicAdds/lane on dst change. Perfect load balance.
//
// Projections: block = 3 waves (Q/K/V roles); lane c keeps W[:,c] in 64 VGPRs;
// row elements broadcast via v_readlane. q pre-scaled by 1/sqrt(d)=0.25;
// dinv[src] folded into packed V.
// ---------------------------------------------------------------------------

#define SEDGE 8

__device__ inline unsigned short bf16_rne(float f) {
    unsigned int u = __float_as_uint(f);
    unsigned int r = u + 0x7FFFu + ((u >> 16) & 1u);
    return (unsigned short)(r >> 16);
}
__device__ inline float kf(unsigned int u) { return __uint_as_float(u << 16); }
__device__ inline float vf(unsigned int u) { return __uint_as_float(u & 0xFFFF0000u); }

__global__ __launch_bounds__(256) void hist_dst_k(const int* __restrict__ dst,
                                                  int* __restrict__ cnt, int E) {
    int e = blockIdx.x * 256 + threadIdx.x;
    if (e < E) atomicAdd(&cnt[dst[e]], 1);
}

// Exclusive scan of (cnt[i]+1), stage 1 (1024-elem chunks); also emits dinv.
__global__ __launch_bounds__(256) void scan1_k(const int* __restrict__ cnt,
                                               int* __restrict__ excl,
                                               int* __restrict__ aux,
                                               float* __restrict__ dinv, int N) {
    __shared__ int wtot[4];
    int b = blockIdx.x, t = threadIdx.x;
    int lane = t & 63, w = t >> 6;
    int base = b * 1024 + t * 4;
    int v0 = (base + 0 < N) ? cnt[base + 0] + 1 : 0;
    int v1 = (base + 1 < N) ? cnt[base + 1] + 1 : 0;
    int v2 = (base + 2 < N) ? cnt[base + 2] + 1 : 0;
    int v3 = (base + 3 < N) ? cnt[base + 3] + 1 : 0;
    if (base + 0 < N) dinv[base + 0] = rsqrtf((float)v0);
    if (base + 1 < N) dinv[base + 1] = rsqrtf((float)v1);
    if (base + 2 < N) dinv[base + 2] = rsqrtf((float)v2);
    if (base + 3 < N) dinv[base + 3] = rsqrtf((float)v3);
    int s = v0 + v1 + v2 + v3;
    int incl = s;
#pragma unroll
    for (int off = 1; off < 64; off <<= 1) {
        int u = __shfl_up(incl, off);
        if (lane >= off) incl += u;
    }
    if (lane == 63) wtot[w] = incl;
    __syncthreads();
    int wb = 0;
#pragma unroll
    for (int j = 0; j < 4; ++j) if (j < w) wb += wtot[j];
    int ex = wb + incl - s;
    if (base + 0 < N) excl[base + 0] = ex;
    if (base + 1 < N) excl[base + 1] = ex + v0;
    if (base + 2 < N) excl[base + 2] = ex + v0 + v1;
    if (base + 3 < N) excl[base + 3] = ex + v0 + v1 + v2;
    if (t == 0) aux[b] = wtot[0] + wtot[1] + wtot[2] + wtot[3];
}

__global__ __launch_bounds__(64) void scan_aux_k(int* __restrict__ aux, int nb,
                                                 int* __restrict__ total) {
    int lane = threadIdx.x;
    int v = (lane < nb) ? aux[lane] : 0;
    int incl = v;
#pragma unroll
    for (int off = 1; off < 64; off <<= 1) {
        int u = __shfl_up(incl, off);
        if (lane >= off) incl += u;
    }
    if (lane < nb) aux[lane] = incl - v;
    if (lane == 63) total[0] = incl;
}

__global__ __launch_bounds__(256) void scan_add_k(int* __restrict__ offs,
                                                  const int* __restrict__ aux,
                                                  int* __restrict__ cursor, int N) {
    int i = blockIdx.x * 256 + threadIdx.x;
    if (i < N) {
        int o = offs[i] + aux[i >> 10];
        offs[i] = o;
        cursor[i] = o;
    }
}

// Writes src and dst per sorted position (grouped by dst).
__global__ __launch_bounds__(256) void scatter_dst_k(const int* __restrict__ src,
                                                     const int* __restrict__ dst,
                                                     int* __restrict__ cursor,
                                                     int* __restrict__ src_sorted,
                                                     int* __restrict__ dst_sorted,
                                                     int E, int N) {
    int e = blockIdx.x * 256 + threadIdx.x;
    int M = E + N;
    if (e >= M) return;
    int s, d;
    if (e < E) { s = src[e]; d = dst[e]; }
    else       { s = d = e - E; }
    int pos = atomicAdd(&cursor[d], 1);
    src_sorted[pos] = s;
    dst_sorted[pos] = d;
}

// h[N x 64] = x[N x 128] @ W[128 x 64] + b ; 16 rows/block (4 rows/thread).
__global__ __launch_bounds__(256) void lin128_64_k(const float* __restrict__ x,
                                                   const float* __restrict__ W,
                                                   const float* __restrict__ b,
                                                   float* __restrict__ y, int N) {
    __shared__ float sW[128 * 64];
    __shared__ float sb[64];
    for (int i = threadIdx.x; i < 128 * 64; i += 256) sW[i] = W[i];
    if (threadIdx.x < 64) sb[threadIdx.x] = b[threadIdx.x];
    __syncthreads();
    int w = threadIdx.x >> 6, c = threadIdx.x & 63;
    int r0 = blockIdx.x * 16 + w * 4;
    if (r0 >= N) return;
    const float* xr[4];
#pragma unroll
    for (int j = 0; j < 4; ++j) {
        int r = r0 + j; if (r > N - 1) r = N - 1;
        xr[j] = x + (size_t)r * 128;
    }
    float acc[4];
#pragma unroll
    for (int j = 0; j < 4; ++j) acc[j] = sb[c];
    for (int k = 0; k < 128; ++k) {
        float wv = sW[k * 64 + c];
#pragma unroll
        for (int j = 0; j < 4; ++j) acc[j] = fmaf(xr[j][k], wv, acc[j]);
    }
#pragma unroll
    for (int j = 0; j < 4; ++j) {
        int r = r0 + j;
        if (r < N) y[(size_t)r * 64 + c] = acc[j];
    }
}

// Projection: X (N x 64 fp32) -> q (x0.25), plane chunk l (bf16 k|v), V0 opt.
// Block = 192 threads = 3 waves (roles Q,K,V); lane holds weight column in
// VGPRs; row broadcast via readlane. RPB rows per block.
template <bool WRITE_V0>
__global__ __launch_bounds__(192) void proj_qkv_k(const float* __restrict__ X,
                                                  const float* __restrict__ Wq, const float* __restrict__ bq,
                                                  const float* __restrict__ Wk, const float* __restrict__ bk,
                                                  const float* __restrict__ Wv, const float* __restrict__ bv,
                                                  const float* __restrict__ dinv,
                                                  float* __restrict__ q,
                                                  unsigned int* __restrict__ PL,
                                                  unsigned short* __restrict__ V0,
                                                  int N, int l, int RPB) {
    int w = threadIdx.x >> 6;    // role: 0=Q 1=K 2=V
    int c = threadIdx.x & 63;
    const float* W = (w == 0) ? Wq : (w == 1) ? Wk : Wv;
    const float* B = (w == 0) ? bq : (w == 1) ? bk : bv;
    float wr[64];
#pragma unroll
    for (int k = 0; k < 64; ++k) wr[k] = W[k * 64 + c];
    float bias = B[c];
    int r0 = blockIdx.x * RPB;
    int r1 = r0 + RPB; if (r1 > N) r1 = N;
    unsigned short* PLh = (unsigned short*)PL;
    for (int r = r0; r < r1; ++r) {
        float xv = X[(size_t)r * 64 + c];
        float a = bias;
#pragma unroll
        for (int k = 0; k < 64; ++k) {
            float xk = __int_as_float(__builtin_amdgcn_readlane(__float_as_int(xv), k));
            a = fmaf(xk, wr[k], a);
        }
        if (w == 0) {
            q[(size_t)r * 64 + c] = a * 0.25f;           // fold 1/sqrt(16)
        } else if (w == 1) {
            PLh[((size_t)r * 192 + l * 64 + c) * 2] = bf16_rne(a);
        } else {
            unsigned short vb = bf16_rne(a * dinv[r]);
            PLh[((size_t)r * 192 + l * 64 + c) * 2 + 1] = vb;
            if (WRITE_V0) V0[(size_t)r * 64 + c] = vb;
        }
    }
}

// Strip-parallel segmented attention. 16-lane group owns SEDGE edges of the
// dst-sorted list; lane holds dims 4*gl..4*gl+3; flush via atomicAdd.
template <int L>
__global__ __launch_bounds__(256) void attn_strip_k(const int* __restrict__ src_sorted,
                                                    const int* __restrict__ dst_sorted,
                                                    const float* __restrict__ dinv,
                                                    const float* __restrict__ q,   // pre-scaled
                                                    const uint4* __restrict__ PL4, // [node][48]
                                                    const unsigned short* __restrict__ V0,
                                                    float* __restrict__ out, int M) {
    int g  = (blockIdx.x * 256 + threadIdx.x) >> 4;   // global group
    int gl = threadIdx.x & 15;
    long base = (long)g * SEDGE;
    if (base >= M) return;

    int   cur_d = -1;
    float dv = 0.f;
    float4 qv = make_float4(0.f, 0.f, 0.f, 0.f);
    float a0 = 0.f, a1 = 0.f, a2 = 0.f, a3 = 0.f;

    for (int i = 0; i < SEDGE; ++i) {
        long pos = base + i;
        if (pos >= M) break;                // only last group breaks early
        int s = src_sorted[pos];
        int d = dst_sorted[pos];
        if (d != cur_d) {
            if (cur_d >= 0) {
                float* op = out + (size_t)cur_d * 64 + gl * 4;
                atomicAdd(op + 0, a0 * dv);
                atomicAdd(op + 1, a1 * dv);
                atomicAdd(op + 2, a2 * dv);
                atomicAdd(op + 3, a3 * dv);
                a0 = a1 = a2 = a3 = 0.f;
            }
            cur_d = d;
            dv = dinv[d];
            if (L > 1) qv = *(const float4*)(q + (size_t)d * 64 + gl * 4);
        }
        if (L == 1) {
            uint2 raw = *(const uint2*)(V0 + (size_t)s * 64 + gl * 4);
            a0 += kf(raw.x);  a1 += vf(raw.x) ;
            a2 += kf(raw.y);  a3 += vf(raw.y);
        } else {
            const uint4* p = PL4 + (size_t)s * 48 + gl;
            uint4 u0 = p[0];
            uint4 u1 = p[16];
            uint4 u2 = u0;
            if (L > 2) u2 = p[32];
            float p0 = qv.x * kf(u0.x);
            p0 = fmaf(qv.y, kf(u0.y), p0);
            p0 = fmaf(qv.z, kf(u0.z), p0);
            p0 = fmaf(qv.w, kf(u0.w), p0);
            float p1 = qv.x * kf(u1.x);
            p1 = fmaf(qv.y, kf(u1.y), p1);
            p1 = fmaf(qv.z, kf(u1.z), p1);
            p1 = fmaf(qv.w, kf(u1.w), p1);
            float p2 = 0.f;
            if (L > 2) {
                p2 = qv.x * kf(u2.x);
                p2 = fmaf(qv.y, kf(u2.y), p2);
                p2 = fmaf(qv.z, kf(u2.z), p2);
                p2 = fmaf(qv.w, kf(u2.w), p2);
            }
            // head reduce: lanes {4h..4h+3} hold head h partials
            p0 += __shfl_xor(p0, 1); p0 += __shfl_xor(p0, 2);
            p1 += __shfl_xor(p1, 1); p1 += __shfl_xor(p1, 2);
            if (L > 2) { p2 += __shfl_xor(p2, 1); p2 += __shfl_xor(p2, 2); }
            float w0, w1, w2;
            if (L == 2) {
                float e = __expf(p1 - p0);
                w0 = __builtin_amdgcn_rcpf(1.0f + e);
                w1 = 1.0f - w0;
                w2 = 0.f;
            } else {
                float mx = fmaxf(fmaxf(p0, p1), p2);
                float e0 = __expf(p0 - mx);
                float e1 = __expf(p1 - mx);
                float e2 = __expf(p2 - mx);
                float inv = __builtin_amdgcn_rcpf(e0 + e1 + e2);
                w0 = e0 * inv; w1 = e1 * inv; w2 = e2 * inv;
            }
            a0 = fmaf(w0, vf(u0.x), a0);
            a1 = fmaf(w0, vf(u0.y), a1);
            a2 = fmaf(w0, vf(u0.z), a2);
            a3 = fmaf(w0, vf(u0.w), a3);
            a0 = fmaf(w1, vf(u1.x), a0);
            a1 = fmaf(w1, vf(u1.y), a1);
            a2 = fmaf(w1, vf(u1.z), a2);
            a3 = fmaf(w1, vf(u1.w), a3);
            if (L > 2) {
                a0 = fmaf(w2, vf(u2.x), a0);
                a1 = fmaf(w2, vf(u2.y), a1);
                a2 = fmaf(w2, vf(u2.z), a2);
                a3 = fmaf(w2, vf(u2.w), a3);
            }
        }
    }
    if (cur_d >= 0) {
        float* op = out + (size_t)cur_d * 64 + gl * 4;
        atomicAdd(op + 0, a0 * dv);
        atomicAdd(op + 1, a1 * dv);
        atomicAdd(op + 2, a2 * dv);
        atomicAdd(op + 3, a3 * dv);
    }
}

// y[N x 16] = xs[N x 64] @ W[64 x 16] + b
__global__ __launch_bounds__(256) void out_proj_k(const float* __restrict__ xs,
                                                  const float* __restrict__ W,
                                                  const float* __restrict__ b,
                                                  float* __restrict__ y, int N) {
    __shared__ float sW[64 * 16];
    __shared__ float sb[16];
    for (int i = threadIdx.x; i < 64 * 16; i += 256) sW[i] = W[i];
    if (threadIdx.x < 16) sb[threadIdx.x] = b[threadIdx.x];
    __syncthreads();
    int row = blockIdx.x * 16 + (threadIdx.x >> 4);
    int c   = threadIdx.x & 15;
    if (row >= N) return;
    const float* xr = xs + (size_t)row * 64;
    float acc = sb[c];
#pragma unroll 16
    for (int k = 0; k < 64; ++k) acc = fmaf(xr[k], sW[k * 16 + c], acc);
    y[(size_t)row * 16 + c] = acc;
}

extern "C" void kernel_launch(void* const* d_in, const int* in_sizes, int n_in,
                              void* d_out, int out_size, void* d_ws, size_t ws_size,
                              hipStream_t stream) {
    const float* x     = (const float*)d_in[0];
    const int*   ei    = (const int*)d_in[1];
    const float* W_lin = (const float*)d_in[2];
    const float* b_lin = (const float*)d_in[3];
    const float* Wq    = (const float*)d_in[4];
    const float* bq    = (const float*)d_in[5];
    const float* Wk    = (const float*)d_in[6];
    const float* bk    = (const float*)d_in[7];
    const float* Wv    = (const float*)d_in[8];
    const float* bv    = (const float*)d_in[9];
    const float* W_out = (const float*)d_in[10];
    const float* b_out = (const float*)d_in[11];
    float* out = (float*)d_out;

    const int N = in_sizes[0] / 128;
    const int E = in_sizes[1] / 2;
    const int M = E + N;
    const int* srcp = ei;
    const int* dstp = ei + E;

    char* wsb = (char*)d_ws;
    float*          dinv       = (float*)wsb;           wsb += (size_t)N * sizeof(float);
    int*            cnt        = (int*)wsb;             wsb += (size_t)N * sizeof(int);
    int*            offs       = (int*)wsb;             wsb += (size_t)(N + 1) * sizeof(int);
    int*            cursor     = (int*)wsb;             wsb += (size_t)N * sizeof(int);
    int*            aux        = (int*)wsb;             wsb += 64 * sizeof(int);
    int*            src_sorted = (int*)wsb;             wsb += (size_t)M * sizeof(int);
    int*            dst_sorted = (int*)wsb;             wsb += (size_t)M * sizeof(int);
    float*          qb         = (float*)wsb;           wsb += (size_t)N * 64 * sizeof(float);
    unsigned int*   PL         = (unsigned int*)wsb;    wsb += (size_t)N * 192 * sizeof(unsigned int);
    unsigned short* V0p        = (unsigned short*)wsb;  wsb += (size_t)N * 64 * sizeof(unsigned short);
    float*          hA         = (float*)wsb;           wsb += (size_t)N * 64 * sizeof(float);
    float*          outb       = (float*)wsb;

    const int gN   = (N + 255) / 256;
    const int gE   = (E + 255) / 256;
    const int gM   = (M + 255) / 256;
    const int g16  = (N + 15) / 16;
    const int nb   = (N + 1023) / 1024;
    const int RPB  = 16;
    const int gP   = (N + RPB - 1) / RPB;
    const int ngrp = (M + SEDGE - 1) / SEDGE;          // 16-lane groups
    const int gA   = (ngrp + 15) / 16;                 // 256-thr blocks

    // degree -> dinv + dst-CSR (src+dst sorted arrays)
    hipMemsetAsync(cnt, 0, (size_t)N * sizeof(int), stream);
    hist_dst_k<<<gE, 256, 0, stream>>>(dstp, cnt, E);
    scan1_k<<<nb, 256, 0, stream>>>(cnt, offs, aux, dinv, N);
    scan_aux_k<<<1, 64, 0, stream>>>(aux, nb, offs + N);
    scan_add_k<<<gN, 256, 0, stream>>>(offs, aux, cursor, N);
    scatter_dst_k<<<gM, 256, 0, stream>>>(srcp, dstp, cursor, src_sorted, dst_sorted, E, N);

    // slice 0: h = x@W_lin + b -> project/pack chunk 0 (+V0)
    lin128_64_k<<<g16, 256, 0, stream>>>(x, W_lin, b_lin, hA, N);
    proj_qkv_k<true><<<gP, 192, 0, stream>>>(hA, Wq, bq, Wk, bk, Wv, bv, dinv,
                                             qb, PL, V0p, N, 0, RPB);

    const uint4* PL4 = (const uint4*)PL;
    const size_t outBytes = (size_t)N * 64 * sizeof(float);

    // layer 1
    hipMemsetAsync(outb, 0, outBytes, stream);
    attn_strip_k<1><<<gA, 256, 0, stream>>>(src_sorted, dst_sorted, dinv, qb, PL4, V0p, outb, M);
    proj_qkv_k<false><<<gP, 192, 0, stream>>>(outb, Wq, bq, Wk, bk, Wv, bv, dinv,
                                              qb, PL, V0p, N, 1, RPB);
    // layer 2
    hipMemsetAsync(outb, 0, outBytes, stream);
    attn_strip_k<2><<<gA, 256, 0, stream>>>(src_sorted, dst_sorted, dinv, qb, PL4, V0p, outb, M);
    proj_qkv_k<false><<<gP, 192, 0, stream>>>(outb, Wq, bq, Wk, bk, Wv, bv, dinv,
                                              qb, PL, V0p, N, 2, RPB);
    // layer 3
    hipMemsetAsync(outb, 0, outBytes, stream);
    attn_strip_k<3><<<gA, 256, 0, stream>>>(src_sorted, dst_sorted, dinv, qb, PL4, V0p, outb, M);

    // final projection
    out_proj_k<<<g16, 256, 0, stream>>>(outb, W_out, b_out, out, N);
}

// Round 8
// 495.213 us; speedup vs baseline: 1.3968x; 1.3968x over previous
//
#include <hip/hip_runtime.h>

// ---------------------------------------------------------------------------
// DNANet round 8: round-5 gather attention (fastest measured) + round-7
// register-stationary projections (no LDS, readlane broadcast).
// N=50000, E=600000 (+N self loops), HID=64, HEADS=4, d=16.
//
// PL[node][l][dim] u32 = bf16(k_l) | bf16(v_l * dinv[node])<<16  (768 B/node)
// V0[node][dim]    u16 = bf16(v_0 * dinv[node])                  (128 B/node)
// q pre-scaled by 1/sqrt(d)=0.25.  attn: one dst node per 64-lane wave,
// L dword gathers per edge, softmax over L slices, coalesced row write.
// ---------------------------------------------------------------------------

__device__ inline unsigned short bf16_rne(float f) {
    unsigned int u = __float_as_uint(f);
    unsigned int r = u + 0x7FFFu + ((u >> 16) & 1u);
    return (unsigned short)(r >> 16);
}

__global__ __launch_bounds__(256) void hist_dst_k(const int* __restrict__ dst,
                                                  int* __restrict__ cnt, int E) {
    int e = blockIdx.x * 256 + threadIdx.x;
    if (e < E) atomicAdd(&cnt[dst[e]], 1);
}

// Exclusive scan of (cnt[i]+1), stage 1 (1024-elem chunks); also emits dinv.
__global__ __launch_bounds__(256) void scan1_k(const int* __restrict__ cnt,
                                               int* __restrict__ excl,
                                               int* __restrict__ aux,
                                               float* __restrict__ dinv, int N) {
    __shared__ int wtot[4];
    int b = blockIdx.x, t = threadIdx.x;
    int lane = t & 63, w = t >> 6;
    int base = b * 1024 + t * 4;
    int v0 = (base + 0 < N) ? cnt[base + 0] + 1 : 0;
    int v1 = (base + 1 < N) ? cnt[base + 1] + 1 : 0;
    int v2 = (base + 2 < N) ? cnt[base + 2] + 1 : 0;
    int v3 = (base + 3 < N) ? cnt[base + 3] + 1 : 0;
    if (base + 0 < N) dinv[base + 0] = rsqrtf((float)v0);
    if (base + 1 < N) dinv[base + 1] = rsqrtf((float)v1);
    if (base + 2 < N) dinv[base + 2] = rsqrtf((float)v2);
    if (base + 3 < N) dinv[base + 3] = rsqrtf((float)v3);
    int s = v0 + v1 + v2 + v3;
    int incl = s;
#pragma unroll
    for (int off = 1; off < 64; off <<= 1) {
        int u = __shfl_up(incl, off);
        if (lane >= off) incl += u;
    }
    if (lane == 63) wtot[w] = incl;
    __syncthreads();
    int wb = 0;
#pragma unroll
    for (int j = 0; j < 4; ++j) if (j < w) wb += wtot[j];
    int ex = wb + incl - s;
    if (base + 0 < N) excl[base + 0] = ex;
    if (base + 1 < N) excl[base + 1] = ex + v0;
    if (base + 2 < N) excl[base + 2] = ex + v0 + v1;
    if (base + 3 < N) excl[base + 3] = ex + v0 + v1 + v2;
    if (t == 0) aux[b] = wtot[0] + wtot[1] + wtot[2] + wtot[3];
}

__global__ __launch_bounds__(64) void scan_aux_k(int* __restrict__ aux, int nb,
                                                 int* __restrict__ total) {
    int lane = threadIdx.x;
    int v = (lane < nb) ? aux[lane] : 0;
    int incl = v;
#pragma unroll
    for (int off = 1; off < 64; off <<= 1) {
        int u = __shfl_up(incl, off);
        if (lane >= off) incl += u;
    }
    if (lane < nb) aux[lane] = incl - v;
    if (lane == 63) total[0] = incl;
}

__global__ __launch_bounds__(256) void scan_add_k(int* __restrict__ offs,
                                                  const int* __restrict__ aux,
                                                  int* __restrict__ cursor, int N) {
    int i = blockIdx.x * 256 + threadIdx.x;
    if (i < N) {
        int o = offs[i] + aux[i >> 10];
        offs[i] = o;
        cursor[i] = o;
    }
}

__global__ __launch_bounds__(256) void scatter_dst_k(const int* __restrict__ src,
                                                     const int* __restrict__ dst,
                                                     int* __restrict__ cursor,
                                                     int* __restrict__ src_sorted,
                                                     int E, int N) {
    int e = blockIdx.x * 256 + threadIdx.x;
    int M = E + N;
    if (e >= M) return;
    int s, d;
    if (e < E) { s = src[e]; d = dst[e]; }
    else       { s = d = e - E; }
    int pos = atomicAdd(&cursor[d], 1);
    src_sorted[pos] = s;
}

// h[N x 64] = x[N x 128] @ W[128 x 64] + b ; 16 rows/block (4 rows/thread).
__global__ __launch_bounds__(256) void lin128_64_k(const float* __restrict__ x,
                                                   const float* __restrict__ W,
                                                   const float* __restrict__ b,
                                                   float* __restrict__ y, int N) {
    __shared__ float sW[128 * 64];
    __shared__ float sb[64];
    for (int i = threadIdx.x; i < 128 * 64; i += 256) sW[i] = W[i];
    if (threadIdx.x < 64) sb[threadIdx.x] = b[threadIdx.x];
    __syncthreads();
    int w = threadIdx.x >> 6, c = threadIdx.x & 63;
    int r0 = blockIdx.x * 16 + w * 4;
    if (r0 >= N) return;
    const float* xr[4];
#pragma unroll
    for (int j = 0; j < 4; ++j) {
        int r = r0 + j; if (r > N - 1) r = N - 1;
        xr[j] = x + (size_t)r * 128;
    }
    float acc[4];
#pragma unroll
    for (int j = 0; j < 4; ++j) acc[j] = sb[c];
    for (int k = 0; k < 128; ++k) {
        float wv = sW[k * 64 + c];
#pragma unroll
        for (int j = 0; j < 4; ++j) acc[j] = fmaf(xr[j][k], wv, acc[j]);
    }
#pragma unroll
    for (int j = 0; j < 4; ++j) {
        int r = r0 + j;
        if (r < N) y[(size_t)r * 64 + c] = acc[j];
    }
}

// Projection: X (N x 64 fp32) -> q (x0.25), PL chunk l (bf16 k|v), V0 opt.
// Block = 192 threads = 3 waves (roles Q,K,V); lane holds W[:,c] in VGPRs;
// row elements broadcast via readlane. RPB rows per block.
template <bool WRITE_V0>
__global__ __launch_bounds__(192) void proj_qkv_k(const float* __restrict__ X,
                                                  const float* __restrict__ Wq, const float* __restrict__ bq,
                                                  const float* __restrict__ Wk, const float* __restrict__ bk,
                                                  const float* __restrict__ Wv, const float* __restrict__ bv,
                                                  const float* __restrict__ dinv,
                                                  float* __restrict__ q,
                                                  unsigned int* __restrict__ PL,
                                                  unsigned short* __restrict__ V0,
                                                  int N, int l, int RPB) {
    int w = threadIdx.x >> 6;    // role: 0=Q 1=K 2=V
    int c = threadIdx.x & 63;
    const float* W = (w == 0) ? Wq : (w == 1) ? Wk : Wv;
    const float* B = (w == 0) ? bq : (w == 1) ? bk : bv;
    float wr[64];
#pragma unroll
    for (int k = 0; k < 64; ++k) wr[k] = W[k * 64 + c];
    float bias = B[c];
    int r0 = blockIdx.x * RPB;
    int r1 = r0 + RPB; if (r1 > N) r1 = N;
    unsigned short* PLh = (unsigned short*)PL;
    for (int r = r0; r < r1; ++r) {
        float xv = X[(size_t)r * 64 + c];
        float a = bias;
#pragma unroll
        for (int k = 0; k < 64; ++k) {
            float xk = __int_as_float(__builtin_amdgcn_readlane(__float_as_int(xv), k));
            a = fmaf(xk, wr[k], a);
        }
        if (w == 0) {
            q[(size_t)r * 64 + c] = a * 0.25f;           // fold 1/sqrt(16)
        } else if (w == 1) {
            PLh[((size_t)r * 192 + l * 64 + c) * 2] = bf16_rne(a);
        } else {
            unsigned short vb = bf16_rne(a * dinv[r]);
            PLh[((size_t)r * 192 + l * 64 + c) * 2 + 1] = vb;
            if (WRITE_V0) V0[(size_t)r * 64 + c] = vb;
        }
    }
}

// One dst node per 64-lane wave; L dword (or 1 ushort) gathers per edge.
// q pre-scaled by 0.25. Writes full row (msg * dinv[d]) coalesced.
template <int L>
__global__ __launch_bounds__(256) void attn_dst_k(const int* __restrict__ offs,
                                                  const int* __restrict__ src_sorted,
                                                  const float* __restrict__ dinv,
                                                  const float* __restrict__ q,
                                                  const unsigned int* __restrict__ PL,
                                                  const unsigned short* __restrict__ V0,
                                                  float* __restrict__ out,
                                                  int N) {
    int d    = (blockIdx.x * 256 + threadIdx.x) >> 6;
    int lane = threadIdx.x & 63;
    if (d >= N) return;
    int beg = offs[d], end = offs[d + 1];
    float qv  = (L > 1) ? q[(size_t)d * 64 + lane] : 0.0f;
    float acc = 0.0f;

    for (int base = beg; base < end; base += 64) {
        int m = end - base;
        if (m > 64) m = 64;
        int sid = (base + lane < end) ? src_sorted[base + lane] : 0;
#pragma unroll 4
        for (int i = 0; i < m; ++i) {
            int s = __shfl(sid, i);
            if (L == 1) {
                acc += __uint_as_float((unsigned int)V0[(size_t)s * 64 + lane] << 16);
            } else if (L == 2) {
                const unsigned int* p = PL + (size_t)s * 192;
                unsigned int u0 = p[lane];
                unsigned int u1 = p[64 + lane];
                float k0 = __uint_as_float((u0 & 0xFFFFu) << 16);
                float v0 = __uint_as_float(u0 & 0xFFFF0000u);
                float k1 = __uint_as_float((u1 & 0xFFFFu) << 16);
                float v1 = __uint_as_float(u1 & 0xFFFF0000u);
                float p0 = qv * k0;
                float p1 = qv * k1;
#pragma unroll
                for (int mk = 8; mk >= 1; mk >>= 1) {
                    p0 += __shfl_xor(p0, mk);
                    p1 += __shfl_xor(p1, mk);
                }
                float e  = __expf(p1 - p0);
                float w0 = __builtin_amdgcn_rcpf(1.0f + e);
                float w1 = 1.0f - w0;
                acc = fmaf(w0, v0, acc);
                acc = fmaf(w1, v1, acc);
            } else {
                const unsigned int* p = PL + (size_t)s * 192;
                unsigned int u0 = p[lane];
                unsigned int u1 = p[64 + lane];
                unsigned int u2 = p[128 + lane];
                float k0 = __uint_as_float((u0 & 0xFFFFu) << 16);
                float v0 = __uint_as_float(u0 & 0xFFFF0000u);
                float k1 = __uint_as_float((u1 & 0xFFFFu) << 16);
                float v1 = __uint_as_float(u1 & 0xFFFF0000u);
                float k2 = __uint_as_float((u2 & 0xFFFFu) << 16);
                float v2 = __uint_as_float(u2 & 0xFFFF0000u);
                float p0 = qv * k0;
                float p1 = qv * k1;
                float p2 = qv * k2;
#pragma unroll
                for (int mk = 8; mk >= 1; mk >>= 1) {
                    p0 += __shfl_xor(p0, mk);
                    p1 += __shfl_xor(p1, mk);
                    p2 += __shfl_xor(p2, mk);
                }
                float mx = fmaxf(fmaxf(p0, p1), p2);
                float w0 = __expf(p0 - mx);
                float w1 = __expf(p1 - mx);
                float w2 = __expf(p2 - mx);
                float inv = __builtin_amdgcn_rcpf(w0 + w1 + w2);
                float msg = w0 * v0;
                msg = fmaf(w1, v1, msg);
                msg = fmaf(w2, v2, msg);
                acc = fmaf(msg, inv, acc);
            }
        }
    }
    out[(size_t)d * 64 + lane] = acc * dinv[d];
}

// y[N x 16] = xs[N x 64] @ W[64 x 16] + b
__global__ __launch_bounds__(256) void out_proj_k(const float* __restrict__ xs,
                                                  const float* __restrict__ W,
                                                  const float* __restrict__ b,
                                                  float* __restrict__ y, int N) {
    __shared__ float sW[64 * 16];
    __shared__ float sb[16];
    for (int i = threadIdx.x; i < 64 * 16; i += 256) sW[i] = W[i];
    if (threadIdx.x < 16) sb[threadIdx.x] = b[threadIdx.x];
    __syncthreads();
    int row = blockIdx.x * 16 + (threadIdx.x >> 4);
    int c   = threadIdx.x & 15;
    if (row >= N) return;
    const float* xr = xs + (size_t)row * 64;
    float acc = sb[c];
#pragma unroll 16
    for (int k = 0; k < 64; ++k) acc = fmaf(xr[k], sW[k * 16 + c], acc);
    y[(size_t)row * 16 + c] = acc;
}

extern "C" void kernel_launch(void* const* d_in, const int* in_sizes, int n_in,
                              void* d_out, int out_size, void* d_ws, size_t ws_size,
                              hipStream_t stream) {
    const float* x     = (const float*)d_in[0];
    const int*   ei    = (const int*)d_in[1];
    const float* W_lin = (const float*)d_in[2];
    const float* b_lin = (const float*)d_in[3];
    const float* Wq    = (const float*)d_in[4];
    const float* bq    = (const float*)d_in[5];
    const float* Wk    = (const float*)d_in[6];
    const float* bk    = (const float*)d_in[7];
    const float* Wv    = (const float*)d_in[8];
    const float* bv    = (const float*)d_in[9];
    const float* W_out = (const float*)d_in[10];
    const float* b_out = (const float*)d_in[11];
    float* out = (float*)d_out;

    const int N = in_sizes[0] / 128;
    const int E = in_sizes[1] / 2;
    const int M = E + N;
    const int* srcp = ei;
    const int* dstp = ei + E;

    char* wsb = (char*)d_ws;
    float*          dinv       = (float*)wsb;           wsb += (size_t)N * sizeof(float);
    int*            cnt        = (int*)wsb;             wsb += (size_t)N * sizeof(int);
    int*            offs       = (int*)wsb;             wsb += (size_t)(N + 1) * sizeof(int);
    int*            cursor     = (int*)wsb;             wsb += (size_t)N * sizeof(int);
    int*            aux        = (int*)wsb;             wsb += 64 * sizeof(int);
    int*            src_sorted = (int*)wsb;             wsb += (size_t)M * sizeof(int);
    float*          qb         = (float*)wsb;           wsb += (size_t)N * 64 * sizeof(float);
    unsigned int*   PL         = (unsigned int*)wsb;    wsb += (size_t)N * 192 * sizeof(unsigned int);
    unsigned short* V0p        = (unsigned short*)wsb;  wsb += (size_t)N * 64 * sizeof(unsigned short);
    float*          hA         = (float*)wsb;           wsb += (size_t)N * 64 * sizeof(float);
    float*          outb       = (float*)wsb;

    const int gN   = (N + 255) / 256;
    const int gE   = (E + 255) / 256;
    const int gM   = (M + 255) / 256;
    const int gRow = (N + 3) / 4;          // attn: 4 waves (nodes) per block
    const int g16  = (N + 15) / 16;
    const int nb   = (N + 1023) / 1024;
    const int RPB  = 16;
    const int gP   = (N + RPB - 1) / RPB;

    // degree -> dinv + dst-CSR
    hipMemsetAsync(cnt, 0, (size_t)N * sizeof(int), stream);
    hist_dst_k<<<gE, 256, 0, stream>>>(dstp, cnt, E);
    scan1_k<<<nb, 256, 0, stream>>>(cnt, offs, aux, dinv, N);
    scan_aux_k<<<1, 64, 0, stream>>>(aux, nb, offs + N);
    scan_add_k<<<gN, 256, 0, stream>>>(offs, aux, cursor, N);
    scatter_dst_k<<<gM, 256, 0, stream>>>(srcp, dstp, cursor, src_sorted, E, N);

    // slice 0: h = x@W_lin + b -> project/pack chunk 0 (+V0)
    lin128_64_k<<<g16, 256, 0, stream>>>(x, W_lin, b_lin, hA, N);
    proj_qkv_k<true><<<gP, 192, 0, stream>>>(hA, Wq, bq, Wk, bk, Wv, bv, dinv,
                                             qb, PL, V0p, N, 0, RPB);

    // layer 1
    attn_dst_k<1><<<gRow, 256, 0, stream>>>(offs, src_sorted, dinv, qb, PL, V0p, outb, N);
    proj_qkv_k<false><<<gP, 192, 0, stream>>>(outb, Wq, bq, Wk, bk, Wv, bv, dinv,
                                              qb, PL, V0p, N, 1, RPB);
    // layer 2
    attn_dst_k<2><<<gRow, 256, 0, stream>>>(offs, src_sorted, dinv, qb, PL, V0p, outb, N);
    proj_qkv_k<false><<<gP, 192, 0, stream>>>(outb, Wq, bq, Wk, bk, Wv, bv, dinv,
                                              qb, PL, V0p, N, 2, RPB);
    // layer 3
    attn_dst_k<3><<<gRow, 256, 0, stream>>>(offs, src_sorted, dinv, qb, PL, V0p, outb, N);

    // final projection
    out_proj_k<<<g16, 256, 0, stream>>>(outb, W_out, b_out, out, N);
}

// Round 9
// 441.518 us; speedup vs baseline: 1.5667x; 1.1216x over previous
//
#include <hip/hip_runtime.h>

// ---------------------------------------------------------------------------
// DNANet round 9: 16-lane-group gather attention (4 nodes per wave, depth-2
// edge prefetch) + register-stationary projections.
// N=50000, E=600000 (+N self loops), HID=64, HEADS=4, d=16.
//
// PL[node][l][dim] u32 = bf16(k_l) | bf16(v_l * dinv[node])<<16  (768 B/node)
// V0[node][dim]    u16 = bf16(v_0 * dinv[node])                  (128 B/node)
// q pre-scaled by 1/sqrt(d)=0.25.
//
// attn: one dst node per 16-lane group; lane owns dims 4g..4g+3 (uint4/slice);
// head h = lanes 4h..4h+3 (shfl_xor 1,2 reduce). Next edge's loads issued
// before current edge's compute -> 2 edges in flight per group, 8 per wave.
// Group writes its node's row as one coalesced float4 per lane. No atomics.
// ---------------------------------------------------------------------------

__device__ inline unsigned short bf16_rne(float f) {
    unsigned int u = __float_as_uint(f);
    unsigned int r = u + 0x7FFFu + ((u >> 16) & 1u);
    return (unsigned short)(r >> 16);
}
__device__ inline float kf(unsigned int u) { return __uint_as_float(u << 16); }
__device__ inline float vf(unsigned int u) { return __uint_as_float(u & 0xFFFF0000u); }

__global__ __launch_bounds__(256) void hist_dst_k(const int* __restrict__ dst,
                                                  int* __restrict__ cnt, int E) {
    int e = blockIdx.x * 256 + threadIdx.x;
    if (e < E) atomicAdd(&cnt[dst[e]], 1);
}

// Exclusive scan of (cnt[i]+1), stage 1 (1024-elem chunks); also emits dinv.
__global__ __launch_bounds__(256) void scan1_k(const int* __restrict__ cnt,
                                               int* __restrict__ excl,
                                               int* __restrict__ aux,
                                               float* __restrict__ dinv, int N) {
    __shared__ int wtot[4];
    int b = blockIdx.x, t = threadIdx.x;
    int lane = t & 63, w = t >> 6;
    int base = b * 1024 + t * 4;
    int v0 = (base + 0 < N) ? cnt[base + 0] + 1 : 0;
    int v1 = (base + 1 < N) ? cnt[base + 1] + 1 : 0;
    int v2 = (base + 2 < N) ? cnt[base + 2] + 1 : 0;
    int v3 = (base + 3 < N) ? cnt[base + 3] + 1 : 0;
    if (base + 0 < N) dinv[base + 0] = rsqrtf((float)v0);
    if (base + 1 < N) dinv[base + 1] = rsqrtf((float)v1);
    if (base + 2 < N) dinv[base + 2] = rsqrtf((float)v2);
    if (base + 3 < N) dinv[base + 3] = rsqrtf((float)v3);
    int s = v0 + v1 + v2 + v3;
    int incl = s;
#pragma unroll
    for (int off = 1; off < 64; off <<= 1) {
        int u = __shfl_up(incl, off);
        if (lane >= off) incl += u;
    }
    if (lane == 63) wtot[w] = incl;
    __syncthreads();
    int wb = 0;
#pragma unroll
    for (int j = 0; j < 4; ++j) if (j < w) wb += wtot[j];
    int ex = wb + incl - s;
    if (base + 0 < N) excl[base + 0] = ex;
    if (base + 1 < N) excl[base + 1] = ex + v0;
    if (base + 2 < N) excl[base + 2] = ex + v0 + v1;
    if (base + 3 < N) excl[base + 3] = ex + v0 + v1 + v2;
    if (t == 0) aux[b] = wtot[0] + wtot[1] + wtot[2] + wtot[3];
}

__global__ __launch_bounds__(64) void scan_aux_k(int* __restrict__ aux, int nb,
                                                 int* __restrict__ total) {
    int lane = threadIdx.x;
    int v = (lane < nb) ? aux[lane] : 0;
    int incl = v;
#pragma unroll
    for (int off = 1; off < 64; off <<= 1) {
        int u = __shfl_up(incl, off);
        if (lane >= off) incl += u;
    }
    if (lane < nb) aux[lane] = incl - v;
    if (lane == 63) total[0] = incl;
}

__global__ __launch_bounds__(256) void scan_add_k(int* __restrict__ offs,
                                                  const int* __restrict__ aux,
                                                  int* __restrict__ cursor, int N) {
    int i = blockIdx.x * 256 + threadIdx.x;
    if (i < N) {
        int o = offs[i] + aux[i >> 10];
        offs[i] = o;
        cursor[i] = o;
    }
}

__global__ __launch_bounds__(256) void scatter_dst_k(const int* __restrict__ src,
                                                     const int* __restrict__ dst,
                                                     int* __restrict__ cursor,
                                                     int* __restrict__ src_sorted,
                                                     int E, int N) {
    int e = blockIdx.x * 256 + threadIdx.x;
    int M = E + N;
    if (e >= M) return;
    int s, d;
    if (e < E) { s = src[e]; d = dst[e]; }
    else       { s = d = e - E; }
    int pos = atomicAdd(&cursor[d], 1);
    src_sorted[pos] = s;
}

// h[N x 64] = x[N x 128] @ W[128 x 64] + b ; 16 rows/block (4 rows/thread).
__global__ __launch_bounds__(256) void lin128_64_k(const float* __restrict__ x,
                                                   const float* __restrict__ W,
                                                   const float* __restrict__ b,
                                                   float* __restrict__ y, int N) {
    __shared__ float sW[128 * 64];
    __shared__ float sb[64];
    for (int i = threadIdx.x; i < 128 * 64; i += 256) sW[i] = W[i];
    if (threadIdx.x < 64) sb[threadIdx.x] = b[threadIdx.x];
    __syncthreads();
    int w = threadIdx.x >> 6, c = threadIdx.x & 63;
    int r0 = blockIdx.x * 16 + w * 4;
    if (r0 >= N) return;
    const float* xr[4];
#pragma unroll
    for (int j = 0; j < 4; ++j) {
        int r = r0 + j; if (r > N - 1) r = N - 1;
        xr[j] = x + (size_t)r * 128;
    }
    float acc[4];
#pragma unroll
    for (int j = 0; j < 4; ++j) acc[j] = sb[c];
    for (int k = 0; k < 128; ++k) {
        float wv = sW[k * 64 + c];
#pragma unroll
        for (int j = 0; j < 4; ++j) acc[j] = fmaf(xr[j][k], wv, acc[j]);
    }
#pragma unroll
    for (int j = 0; j < 4; ++j) {
        int r = r0 + j;
        if (r < N) y[(size_t)r * 64 + c] = acc[j];
    }
}

// Projection: X (N x 64 fp32) -> q (x0.25), PL chunk l (bf16 k|v), V0 opt.
// Block = 192 threads = 3 waves (roles Q,K,V); lane holds W[:,c] in VGPRs;
// row elements broadcast via readlane. RPB rows per block.
template <bool WRITE_V0>
__global__ __launch_bounds__(192) void proj_qkv_k(const float* __restrict__ X,
                                                  const float* __restrict__ Wq, const float* __restrict__ bq,
                                                  const float* __restrict__ Wk, const float* __restrict__ bk,
                                                  const float* __restrict__ Wv, const float* __restrict__ bv,
                                                  const float* __restrict__ dinv,
                                                  float* __restrict__ q,
                                                  unsigned int* __restrict__ PL,
                                                  unsigned short* __restrict__ V0,
                                                  int N, int l, int RPB) {
    int w = threadIdx.x >> 6;    // role: 0=Q 1=K 2=V
    int c = threadIdx.x & 63;
    const float* W = (w == 0) ? Wq : (w == 1) ? Wk : Wv;
    const float* B = (w == 0) ? bq : (w == 1) ? bk : bv;
    float wr[64];
#pragma unroll
    for (int k = 0; k < 64; ++k) wr[k] = W[k * 64 + c];
    float bias = B[c];
    int r0 = blockIdx.x * RPB;
    int r1 = r0 + RPB; if (r1 > N) r1 = N;
    unsigned short* PLh = (unsigned short*)PL;
    for (int r = r0; r < r1; ++r) {
        float xv = X[(size_t)r * 64 + c];
        float a = bias;
#pragma unroll
        for (int k = 0; k < 64; ++k) {
            float xk = __int_as_float(__builtin_amdgcn_readlane(__float_as_int(xv), k));
            a = fmaf(xk, wr[k], a);
        }
        if (w == 0) {
            q[(size_t)r * 64 + c] = a * 0.25f;           // fold 1/sqrt(16)
        } else if (w == 1) {
            PLh[((size_t)r * 192 + l * 64 + c) * 2] = bf16_rne(a);
        } else {
            unsigned short vb = bf16_rne(a * dinv[r]);
            PLh[((size_t)r * 192 + l * 64 + c) * 2 + 1] = vb;
            if (WRITE_V0) V0[(size_t)r * 64 + c] = vb;
        }
    }
}

// 16-lane-group attention: group owns one dst node; lane owns 4 dims.
// Depth-2 edge prefetch; no atomics (group writes its own row).
template <int L>
__global__ __launch_bounds__(256) void attn_g16_k(const int* __restrict__ offs,
                                                  const int* __restrict__ src_sorted,
                                                  const float* __restrict__ dinv,
                                                  const float* __restrict__ q,
                                                  const unsigned int* __restrict__ PL,
                                                  const unsigned short* __restrict__ V0,
                                                  float* __restrict__ out,
                                                  int N) {
    int d  = (blockIdx.x * 256 + threadIdx.x) >> 4;
    int gl = threadIdx.x & 15;
    int gb = threadIdx.x & 48;            // group base lane within wave
    if (d >= N) return;
    int beg = offs[d], end = offs[d + 1];

    float4 qv = make_float4(0.f, 0.f, 0.f, 0.f);
    if (L > 1) qv = *(const float4*)(q + (size_t)d * 64 + gl * 4);

    float a0 = 0.f, a1 = 0.f, a2 = 0.f, a3 = 0.f;

    for (int base = beg; base < end; base += 16) {
        int m = end - base;
        if (m > 16) m = 16;
        int sid = (base + gl < end) ? src_sorted[base + gl] : 0;

        // current / next register sets (unconditional loads; OOR clamps to m-1)
        uint4 A0, A1, A2, B0, B1, B2;
        uint2 Av, Bv;
        int s0 = __shfl(sid, gb);
        if (L == 1) {
            Av = *(const uint2*)(V0 + (size_t)s0 * 64 + gl * 4);
        } else {
            const uint4* pp = (const uint4*)(PL + (size_t)s0 * 192) + gl;
            A0 = pp[0];
            A1 = pp[16];
            if (L > 2) A2 = pp[32];
        }

        for (int i = 0; i < m; ++i) {
            int nx = i + 1 < m ? i + 1 : m - 1;
            int sn = __shfl(sid, gb + nx);
            if (L == 1) {
                Bv = *(const uint2*)(V0 + (size_t)sn * 64 + gl * 4);
            } else {
                const uint4* pp = (const uint4*)(PL + (size_t)sn * 192) + gl;
                B0 = pp[0];
                B1 = pp[16];
                if (L > 2) B2 = pp[32];
            }

            if (L == 1) {
                a0 += __uint_as_float((Av.x & 0xFFFFu) << 16);
                a1 += __uint_as_float(Av.x & 0xFFFF0000u);
                a2 += __uint_as_float((Av.y & 0xFFFFu) << 16);
                a3 += __uint_as_float(Av.y & 0xFFFF0000u);
            } else {
                float p0 = qv.x * kf(A0.x);
                p0 = fmaf(qv.y, kf(A0.y), p0);
                p0 = fmaf(qv.z, kf(A0.z), p0);
                p0 = fmaf(qv.w, kf(A0.w), p0);
                float p1 = qv.x * kf(A1.x);
                p1 = fmaf(qv.y, kf(A1.y), p1);
                p1 = fmaf(qv.z, kf(A1.z), p1);
                p1 = fmaf(qv.w, kf(A1.w), p1);
                float p2 = 0.f;
                if (L > 2) {
                    p2 = qv.x * kf(A2.x);
                    p2 = fmaf(qv.y, kf(A2.y), p2);
                    p2 = fmaf(qv.z, kf(A2.z), p2);
                    p2 = fmaf(qv.w, kf(A2.w), p2);
                }
                // head reduce within 4-lane cluster
                p0 += __shfl_xor(p0, 1); p0 += __shfl_xor(p0, 2);
                p1 += __shfl_xor(p1, 1); p1 += __shfl_xor(p1, 2);
                if (L > 2) { p2 += __shfl_xor(p2, 1); p2 += __shfl_xor(p2, 2); }
                float w0, w1, w2 = 0.f;
                if (L == 2) {
                    float e = __expf(p1 - p0);
                    w0 = __builtin_amdgcn_rcpf(1.0f + e);
                    w1 = 1.0f - w0;
                } else {
                    float mx = fmaxf(fmaxf(p0, p1), p2);
                    float e0 = __expf(p0 - mx);
                    float e1 = __expf(p1 - mx);
                    float e2 = __expf(p2 - mx);
                    float inv = __builtin_amdgcn_rcpf(e0 + e1 + e2);
                    w0 = e0 * inv; w1 = e1 * inv; w2 = e2 * inv;
                }
                a0 = fmaf(w0, vf(A0.x), a0);
                a1 = fmaf(w0, vf(A0.y), a1);
                a2 = fmaf(w0, vf(A0.z), a2);
                a3 = fmaf(w0, vf(A0.w), a3);
                a0 = fmaf(w1, vf(A1.x), a0);
                a1 = fmaf(w1, vf(A1.y), a1);
                a2 = fmaf(w1, vf(A1.z), a2);
                a3 = fmaf(w1, vf(A1.w), a3);
                if (L > 2) {
                    a0 = fmaf(w2, vf(A2.x), a0);
                    a1 = fmaf(w2, vf(A2.y), a1);
                    a2 = fmaf(w2, vf(A2.z), a2);
                    a3 = fmaf(w2, vf(A2.w), a3);
                }
            }
            if (L == 1) {
                Av = Bv;
            } else {
                A0 = B0; A1 = B1;
                if (L > 2) A2 = B2;
            }
        }
    }
    float dv = dinv[d];
    *(float4*)(out + (size_t)d * 64 + gl * 4) =
        make_float4(a0 * dv, a1 * dv, a2 * dv, a3 * dv);
}

// y[N x 16] = xs[N x 64] @ W[64 x 16] + b
__global__ __launch_bounds__(256) void out_proj_k(const float* __restrict__ xs,
                                                  const float* __restrict__ W,
                                                  const float* __restrict__ b,
                                                  float* __restrict__ y, int N) {
    __shared__ float sW[64 * 16];
    __shared__ float sb[16];
    for (int i = threadIdx.x; i < 64 * 16; i += 256) sW[i] = W[i];
    if (threadIdx.x < 16) sb[threadIdx.x] = b[threadIdx.x];
    __syncthreads();
    int row = blockIdx.x * 16 + (threadIdx.x >> 4);
    int c   = threadIdx.x & 15;
    if (row >= N) return;
    const float* xr = xs + (size_t)row * 64;
    float acc = sb[c];
#pragma unroll 16
    for (int k = 0; k < 64; ++k) acc = fmaf(xr[k], sW[k * 16 + c], acc);
    y[(size_t)row * 16 + c] = acc;
}

extern "C" void kernel_launch(void* const* d_in, const int* in_sizes, int n_in,
                              void* d_out, int out_size, void* d_ws, size_t ws_size,
                              hipStream_t stream) {
    const float* x     = (const float*)d_in[0];
    const int*   ei    = (const int*)d_in[1];
    const float* W_lin = (const float*)d_in[2];
    const float* b_lin = (const float*)d_in[3];
    const float* Wq    = (const float*)d_in[4];
    const float* bq    = (const float*)d_in[5];
    const float* Wk    = (const float*)d_in[6];
    const float* bk    = (const float*)d_in[7];
    const float* Wv    = (const float*)d_in[8];
    const float* bv    = (const float*)d_in[9];
    const float* W_out = (const float*)d_in[10];
    const float* b_out = (const float*)d_in[11];
    float* out = (float*)d_out;

    const int N = in_sizes[0] / 128;
    const int E = in_sizes[1] / 2;
    const int M = E + N;
    const int* srcp = ei;
    const int* dstp = ei + E;

    char* wsb = (char*)d_ws;
    float*          dinv       = (float*)wsb;           wsb += (size_t)N * sizeof(float);
    int*            cnt        = (int*)wsb;             wsb += (size_t)N * sizeof(int);
    int*            offs       = (int*)wsb;             wsb += (size_t)(N + 1) * sizeof(int);
    int*            cursor     = (int*)wsb;             wsb += (size_t)N * sizeof(int);
    int*            aux        = (int*)wsb;             wsb += 64 * sizeof(int);
    int*            src_sorted = (int*)wsb;             wsb += (size_t)M * sizeof(int);
    float*          qb         = (float*)wsb;           wsb += (size_t)N * 64 * sizeof(float);
    unsigned int*   PL         = (unsigned int*)wsb;    wsb += (size_t)N * 192 * sizeof(unsigned int);
    unsigned short* V0p        = (unsigned short*)wsb;  wsb += (size_t)N * 64 * sizeof(unsigned short);
    float*          hA         = (float*)wsb;           wsb += (size_t)N * 64 * sizeof(float);
    float*          outb       = (float*)wsb;

    const int gN   = (N + 255) / 256;
    const int gE   = (E + 255) / 256;
    const int gM   = (M + 255) / 256;
    const int g16  = (N + 15) / 16;        // 16 nodes (groups) per 256-thr block
    const int nb   = (N + 1023) / 1024;
    const int RPB  = 16;
    const int gP   = (N + RPB - 1) / RPB;

    // degree -> dinv + dst-CSR
    hipMemsetAsync(cnt, 0, (size_t)N * sizeof(int), stream);
    hist_dst_k<<<gE, 256, 0, stream>>>(dstp, cnt, E);
    scan1_k<<<nb, 256, 0, stream>>>(cnt, offs, aux, dinv, N);
    scan_aux_k<<<1, 64, 0, stream>>>(aux, nb, offs + N);
    scan_add_k<<<gN, 256, 0, stream>>>(offs, aux, cursor, N);
    scatter_dst_k<<<gM, 256, 0, stream>>>(srcp, dstp, cursor, src_sorted, E, N);

    // slice 0: h = x@W_lin + b -> project/pack chunk 0 (+V0)
    lin128_64_k<<<g16, 256, 0, stream>>>(x, W_lin, b_lin, hA, N);
    proj_qkv_k<true><<<gP, 192, 0, stream>>>(hA, Wq, bq, Wk, bk, Wv, bv, dinv,
                                             qb, PL, V0p, N, 0, RPB);

    // layer 1
    attn_g16_k<1><<<g16, 256, 0, stream>>>(offs, src_sorted, dinv, qb, PL, V0p, outb, N);
    proj_qkv_k<false><<<gP, 192, 0, stream>>>(outb, Wq, bq, Wk, bk, Wv, bv, dinv,
                                              qb, PL, V0p, N, 1, RPB);
    // layer 2
    attn_g16_k<2><<<g16, 256, 0, stream>>>(offs, src_sorted, dinv, qb, PL, V0p, outb, N);
    proj_qkv_k<false><<<gP, 192, 0, stream>>>(outb, Wq, bq, Wk, bk, Wv, bv, dinv,
                                              qb, PL, V0p, N, 2, RPB);
    // layer 3
    attn_g16_k<3><<<g16, 256, 0, stream>>>(offs, src_sorted, dinv, qb, PL, V0p, outb, N);

    // final projection
    out_proj_k<<<g16, 256, 0, stream>>>(outb, W_out, b_out, out, N);
}

// Round 10
// 430.895 us; speedup vs baseline: 1.6053x; 1.0247x over previous
//
#include <hip/hip_runtime.h>

// ---------------------------------------------------------------------------
// DNANet round 10: 16-lane-group gather attention with depth-3 edge prefetch,
// fused W_out epilogue on the last layer, lean 4-kernel CSR preprocessing.
// N=50000, E=600000 (+N self loops), HID=64, HEADS=4, d=16.
//
// PL[node][l][dim] u32 = bf16(k_l) | bf16(v_l * dinv[node])<<16  (768 B/node)
// V0[node][dim]    u16 = bf16(v_0 * dinv[node])                  (128 B/node)
// q pre-scaled by 1/sqrt(d)=0.25.
//
// attn: one dst node per 16-lane group (4/wave); lane owns dims 4g..4g+3;
// depth-3 software pipeline (edges i, i+1, i+2 in flight). Layer 3 stages
// rows in LDS and applies W_out in-block (8 KB LDS), writing d_out directly.
// ---------------------------------------------------------------------------

__device__ inline unsigned short bf16_rne(float f) {
    unsigned int u = __float_as_uint(f);
    unsigned int r = u + 0x7FFFu + ((u >> 16) & 1u);
    return (unsigned short)(r >> 16);
}
__device__ inline float kf(unsigned int u) { return __uint_as_float(u << 16); }
__device__ inline float vf(unsigned int u) { return __uint_as_float(u & 0xFFFF0000u); }

__global__ __launch_bounds__(256) void hist_dst_k(const int* __restrict__ dst,
                                                  int* __restrict__ cnt, int E) {
    int e = blockIdx.x * 256 + threadIdx.x;
    if (e < E) atomicAdd(&cnt[dst[e]], 1);
}

// Exclusive scan of (cnt[i]+1), stage 1 (1024-elem chunks); also emits dinv.
__global__ __launch_bounds__(256) void scan1_k(const int* __restrict__ cnt,
                                               int* __restrict__ excl,
                                               int* __restrict__ aux,
                                               float* __restrict__ dinv, int N) {
    __shared__ int wtot[4];
    int b = blockIdx.x, t = threadIdx.x;
    int lane = t & 63, w = t >> 6;
    int base = b * 1024 + t * 4;
    int v0 = (base + 0 < N) ? cnt[base + 0] + 1 : 0;
    int v1 = (base + 1 < N) ? cnt[base + 1] + 1 : 0;
    int v2 = (base + 2 < N) ? cnt[base + 2] + 1 : 0;
    int v3 = (base + 3 < N) ? cnt[base + 3] + 1 : 0;
    if (base + 0 < N) dinv[base + 0] = rsqrtf((float)v0);
    if (base + 1 < N) dinv[base + 1] = rsqrtf((float)v1);
    if (base + 2 < N) dinv[base + 2] = rsqrtf((float)v2);
    if (base + 3 < N) dinv[base + 3] = rsqrtf((float)v3);
    int s = v0 + v1 + v2 + v3;
    int incl = s;
#pragma unroll
    for (int off = 1; off < 64; off <<= 1) {
        int u = __shfl_up(incl, off);
        if (lane >= off) incl += u;
    }
    if (lane == 63) wtot[w] = incl;
    __syncthreads();
    int wb = 0;
#pragma unroll
    for (int j = 0; j < 4; ++j) if (j < w) wb += wtot[j];
    int ex = wb + incl - s;
    if (base + 0 < N) excl[base + 0] = ex;
    if (base + 1 < N) excl[base + 1] = ex + v0;
    if (base + 2 < N) excl[base + 2] = ex + v0 + v1;
    if (base + 3 < N) excl[base + 3] = ex + v0 + v1 + v2;
    if (t == 0) aux[b] = wtot[0] + wtot[1] + wtot[2] + wtot[3];
}

// Add chunk bases (self-computed: one wave-reduce over raw aux totals),
// mirror into cursor, and write offs[N] from the last element.
__global__ __launch_bounds__(256) void scan_add2_k(int* __restrict__ offs,
                                                   const int* __restrict__ aux,
                                                   const int* __restrict__ cnt,
                                                   int* __restrict__ cursor,
                                                   int N, int nb) {
    int i = blockIdx.x * 256 + threadIdx.x;
    int c = blockIdx.x >> 2;                  // 1024-chunk id (256*4 = 1024)
    int lane = threadIdx.x & 63;
    int v = (lane < c && lane < nb) ? aux[lane] : 0;
#pragma unroll
    for (int off = 32; off >= 1; off >>= 1) v += __shfl_xor(v, off);
    if (i < N) {
        int o = offs[i] + v;
        offs[i] = o;
        cursor[i] = o;
        if (i == N - 1) offs[N] = o + cnt[i] + 1;
    }
}

__global__ __launch_bounds__(256) void scatter_dst_k(const int* __restrict__ src,
                                                     const int* __restrict__ dst,
                                                     int* __restrict__ cursor,
                                                     int* __restrict__ src_sorted,
                                                     int E, int N) {
    int e = blockIdx.x * 256 + threadIdx.x;
    int M = E + N;
    if (e >= M) return;
    int s, d;
    if (e < E) { s = src[e]; d = dst[e]; }
    else       { s = d = e - E; }
    int pos = atomicAdd(&cursor[d], 1);
    src_sorted[pos] = s;
}

// h[N x 64] = x[N x 128] @ W[128 x 64] + b ; 16 rows/block (4 rows/thread).
__global__ __launch_bounds__(256) void lin128_64_k(const float* __restrict__ x,
                                                   const float* __restrict__ W,
                                                   const float* __restrict__ b,
                                                   float* __restrict__ y, int N) {
    __shared__ float sW[128 * 64];
    __shared__ float sb[64];
    for (int i = threadIdx.x; i < 128 * 64; i += 256) sW[i] = W[i];
    if (threadIdx.x < 64) sb[threadIdx.x] = b[threadIdx.x];
    __syncthreads();
    int w = threadIdx.x >> 6, c = threadIdx.x & 63;
    int r0 = blockIdx.x * 16 + w * 4;
    if (r0 >= N) return;
    const float* xr[4];
#pragma unroll
    for (int j = 0; j < 4; ++j) {
        int r = r0 + j; if (r > N - 1) r = N - 1;
        xr[j] = x + (size_t)r * 128;
    }
    float acc[4];
#pragma unroll
    for (int j = 0; j < 4; ++j) acc[j] = sb[c];
    for (int k = 0; k < 128; ++k) {
        float wv = sW[k * 64 + c];
#pragma unroll
        for (int j = 0; j < 4; ++j) acc[j] = fmaf(xr[j][k], wv, acc[j]);
    }
#pragma unroll
    for (int j = 0; j < 4; ++j) {
        int r = r0 + j;
        if (r < N) y[(size_t)r * 64 + c] = acc[j];
    }
}

// Projection: X (N x 64 fp32) -> q (x0.25), PL chunk l (bf16 k|v), V0 opt.
// Block = 192 threads = 3 waves (roles Q,K,V); lane holds W[:,c] in VGPRs;
// row elements broadcast via readlane. RPB rows per block.
template <bool WRITE_V0>
__global__ __launch_bounds__(192) void proj_qkv_k(const float* __restrict__ X,
                                                  const float* __restrict__ Wq, const float* __restrict__ bq,
                                                  const float* __restrict__ Wk, const float* __restrict__ bk,
                                                  const float* __restrict__ Wv, const float* __restrict__ bv,
                                                  const float* __restrict__ dinv,
                                                  float* __restrict__ q,
                                                  unsigned int* __restrict__ PL,
                                                  unsigned short* __restrict__ V0,
                                                  int N, int l, int RPB) {
    int w = threadIdx.x >> 6;    // role: 0=Q 1=K 2=V
    int c = threadIdx.x & 63;
    const float* W = (w == 0) ? Wq : (w == 1) ? Wk : Wv;
    const float* B = (w == 0) ? bq : (w == 1) ? bk : bv;
    float wr[64];
#pragma unroll
    for (int k = 0; k < 64; ++k) wr[k] = W[k * 64 + c];
    float bias = B[c];
    int r0 = blockIdx.x * RPB;
    int r1 = r0 + RPB; if (r1 > N) r1 = N;
    unsigned short* PLh = (unsigned short*)PL;
    for (int r = r0; r < r1; ++r) {
        float xv = X[(size_t)r * 64 + c];
        float a = bias;
#pragma unroll
        for (int k = 0; k < 64; ++k) {
            float xk = __int_as_float(__builtin_amdgcn_readlane(__float_as_int(xv), k));
            a = fmaf(xk, wr[k], a);
        }
        if (w == 0) {
            q[(size_t)r * 64 + c] = a * 0.25f;           // fold 1/sqrt(16)
        } else if (w == 1) {
            PLh[((size_t)r * 192 + l * 64 + c) * 2] = bf16_rne(a);
        } else {
            unsigned short vb = bf16_rne(a * dinv[r]);
            PLh[((size_t)r * 192 + l * 64 + c) * 2 + 1] = vb;
            if (WRITE_V0) V0[(size_t)r * 64 + c] = vb;
        }
    }
}

// 16-lane-group attention, depth-3 pipeline. EMIT_OUT: fused W_out epilogue.
template <int L, bool EMIT_OUT>
__global__ __launch_bounds__(256) void attn_g16_k(const int* __restrict__ offs,
                                                  const int* __restrict__ src_sorted,
                                                  const float* __restrict__ dinv,
                                                  const float* __restrict__ q,
                                                  const unsigned int* __restrict__ PL,
                                                  const unsigned short* __restrict__ V0,
                                                  const float* __restrict__ Wo,
                                                  const float* __restrict__ bo,
                                                  float* __restrict__ outv,   // rows (Nx64) or final (Nx16)
                                                  int N) {
    constexpr int LDSN = EMIT_OUT ? (16 * 68 + 64 * 16 + 16) : 1;
    __shared__ float lds[LDSN];
    float* rowS = lds;                    // [16][68]
    float* sWo  = lds + 16 * 68;          // [64][16]
    float* sbo  = sWo + 64 * 16;          // [16]
    if (EMIT_OUT) {
        for (int i = threadIdx.x; i < 64 * 16; i += 256) sWo[i] = Wo[i];
        if (threadIdx.x < 16) sbo[threadIdx.x] = bo[threadIdx.x];
    }

    int d  = (blockIdx.x * 256 + threadIdx.x) >> 4;
    int gl = threadIdx.x & 15;
    int gb = threadIdx.x & 48;            // group base lane within wave
    float a0 = 0.f, a1 = 0.f, a2 = 0.f, a3 = 0.f;
    float dv = 0.f;

    if (d < N) {
        dv = dinv[d];
        int beg = offs[d], end = offs[d + 1];
        float4 qv = make_float4(0.f, 0.f, 0.f, 0.f);
        if (L > 1) qv = *(const float4*)(q + (size_t)d * 64 + gl * 4);

        for (int base = beg; base < end; base += 16) {
            int m = end - base;
            if (m > 16) m = 16;
            int sid = (base + gl < end) ? src_sorted[base + gl] : 0;
            int mm1 = m - 1;
#define SIDAT(j) __shfl(sid, gb + ((j) < mm1 ? (j) : mm1))
            uint4 A0, A1, A2, B0, B1, B2, C0, C1, C2;
            uint2 Av, Bv, Cv;
            int sA = SIDAT(0), sB = SIDAT(1);
            if (L == 1) {
                Av = *(const uint2*)(V0 + (size_t)sA * 64 + gl * 4);
                Bv = *(const uint2*)(V0 + (size_t)sB * 64 + gl * 4);
            } else {
                const uint4* pa = (const uint4*)(PL + (size_t)sA * 192) + gl;
                A0 = pa[0]; A1 = pa[16]; if (L > 2) A2 = pa[32];
                const uint4* pb = (const uint4*)(PL + (size_t)sB * 192) + gl;
                B0 = pb[0]; B1 = pb[16]; if (L > 2) B2 = pb[32];
            }

            for (int i = 0; i < m; ++i) {
                int sC = SIDAT(i + 2);
                if (L == 1) {
                    Cv = *(const uint2*)(V0 + (size_t)sC * 64 + gl * 4);
                } else {
                    const uint4* pc = (const uint4*)(PL + (size_t)sC * 192) + gl;
                    C0 = pc[0]; C1 = pc[16]; if (L > 2) C2 = pc[32];
                }

                if (L == 1) {
                    a0 += __uint_as_float((Av.x & 0xFFFFu) << 16);
                    a1 += __uint_as_float(Av.x & 0xFFFF0000u);
                    a2 += __uint_as_float((Av.y & 0xFFFFu) << 16);
                    a3 += __uint_as_float(Av.y & 0xFFFF0000u);
                } else {
                    float p0 = qv.x * kf(A0.x);
                    p0 = fmaf(qv.y, kf(A0.y), p0);
                    p0 = fmaf(qv.z, kf(A0.z), p0);
                    p0 = fmaf(qv.w, kf(A0.w), p0);
                    float p1 = qv.x * kf(A1.x);
                    p1 = fmaf(qv.y, kf(A1.y), p1);
                    p1 = fmaf(qv.z, kf(A1.z), p1);
                    p1 = fmaf(qv.w, kf(A1.w), p1);
                    float p2 = 0.f;
                    if (L > 2) {
                        p2 = qv.x * kf(A2.x);
                        p2 = fmaf(qv.y, kf(A2.y), p2);
                        p2 = fmaf(qv.z, kf(A2.z), p2);
                        p2 = fmaf(qv.w, kf(A2.w), p2);
                    }
                    p0 += __shfl_xor(p0, 1); p0 += __shfl_xor(p0, 2);
                    p1 += __shfl_xor(p1, 1); p1 += __shfl_xor(p1, 2);
                    if (L > 2) { p2 += __shfl_xor(p2, 1); p2 += __shfl_xor(p2, 2); }
                    float w0, w1, w2 = 0.f;
                    if (L == 2) {
                        float e = __expf(p1 - p0);
                        w0 = __builtin_amdgcn_rcpf(1.0f + e);
                        w1 = 1.0f - w0;
                    } else {
                        float mx = fmaxf(fmaxf(p0, p1), p2);
                        float e0 = __expf(p0 - mx);
                        float e1 = __expf(p1 - mx);
                        float e2 = __expf(p2 - mx);
                        float inv = __builtin_amdgcn_rcpf(e0 + e1 + e2);
                        w0 = e0 * inv; w1 = e1 * inv; w2 = e2 * inv;
                    }
                    a0 = fmaf(w0, vf(A0.x), a0);
                    a1 = fmaf(w0, vf(A0.y), a1);
                    a2 = fmaf(w0, vf(A0.z), a2);
                    a3 = fmaf(w0, vf(A0.w), a3);
                    a0 = fmaf(w1, vf(A1.x), a0);
                    a1 = fmaf(w1, vf(A1.y), a1);
                    a2 = fmaf(w1, vf(A1.z), a2);
                    a3 = fmaf(w1, vf(A1.w), a3);
                    if (L > 2) {
                        a0 = fmaf(w2, vf(A2.x), a0);
                        a1 = fmaf(w2, vf(A2.y), a1);
                        a2 = fmaf(w2, vf(A2.z), a2);
                        a3 = fmaf(w2, vf(A2.w), a3);
                    }
                }
                if (L == 1) {
                    Av = Bv; Bv = Cv;
                } else {
                    A0 = B0; A1 = B1; B0 = C0; B1 = C1;
                    if (L > 2) { A2 = B2; B2 = C2; }
                }
            }
#undef SIDAT
        }
    }

    if (EMIT_OUT) {
        int w16 = threadIdx.x >> 4;
        if (d < N) {
            rowS[w16 * 68 + gl * 4 + 0] = a0 * dv;
            rowS[w16 * 68 + gl * 4 + 1] = a1 * dv;
            rowS[w16 * 68 + gl * 4 + 2] = a2 * dv;
            rowS[w16 * 68 + gl * 4 + 3] = a3 * dv;
        }
        __syncthreads();
        int node = threadIdx.x >> 4;
        int co   = threadIdx.x & 15;
        int dn   = blockIdx.x * 16 + node;
        if (dn < N) {
            float acc = sbo[co];
#pragma unroll 16
            for (int k = 0; k < 64; ++k)
                acc = fmaf(rowS[node * 68 + k], sWo[k * 16 + co], acc);
            outv[(size_t)dn * 16 + co] = acc;
        }
    } else {
        if (d < N)
            *(float4*)(outv + (size_t)d * 64 + gl * 4) =
                make_float4(a0 * dv, a1 * dv, a2 * dv, a3 * dv);
    }
}

extern "C" void kernel_launch(void* const* d_in, const int* in_sizes, int n_in,
                              void* d_out, int out_size, void* d_ws, size_t ws_size,
                              hipStream_t stream) {
    const float* x     = (const float*)d_in[0];
    const int*   ei    = (const int*)d_in[1];
    const float* W_lin = (const float*)d_in[2];
    const float* b_lin = (const float*)d_in[3];
    const float* Wq    = (const float*)d_in[4];
    const float* bq    = (const float*)d_in[5];
    const float* Wk    = (const float*)d_in[6];
    const float* bk    = (const float*)d_in[7];
    const float* Wv    = (const float*)d_in[8];
    const float* bv    = (const float*)d_in[9];
    const float* W_out = (const float*)d_in[10];
    const float* b_out = (const float*)d_in[11];
    float* out = (float*)d_out;

    const int N = in_sizes[0] / 128;
    const int E = in_sizes[1] / 2;
    const int M = E + N;
    const int* srcp = ei;
    const int* dstp = ei + E;

    char* wsb = (char*)d_ws;
    float*          dinv       = (float*)wsb;           wsb += (size_t)N * sizeof(float);
    int*            cnt        = (int*)wsb;             wsb += (size_t)N * sizeof(int);
    int*            offs       = (int*)wsb;             wsb += (size_t)(N + 1) * sizeof(int);
    int*            cursor     = (int*)wsb;             wsb += (size_t)N * sizeof(int);
    int*            aux        = (int*)wsb;             wsb += 64 * sizeof(int);
    int*            src_sorted = (int*)wsb;             wsb += (size_t)M * sizeof(int);
    float*          qb         = (float*)wsb;           wsb += (size_t)N * 64 * sizeof(float);
    unsigned int*   PL         = (unsigned int*)wsb;    wsb += (size_t)N * 192 * sizeof(unsigned int);
    unsigned short* V0p        = (unsigned short*)wsb;  wsb += (size_t)N * 64 * sizeof(unsigned short);
    float*          hA         = (float*)wsb;           wsb += (size_t)N * 64 * sizeof(float);
    float*          outb       = (float*)wsb;

    const int gN   = (N + 255) / 256;
    const int gE   = (E + 255) / 256;
    const int gM   = (M + 255) / 256;
    const int g16  = (N + 15) / 16;        // 16 nodes (groups) per 256-thr block
    const int nb   = (N + 1023) / 1024;
    const int RPB  = 16;
    const int gP   = (N + RPB - 1) / RPB;

    // degree -> dinv + dst-CSR (4 kernels + memset)
    hipMemsetAsync(cnt, 0, (size_t)N * sizeof(int), stream);
    hist_dst_k<<<gE, 256, 0, stream>>>(dstp, cnt, E);
    scan1_k<<<nb, 256, 0, stream>>>(cnt, offs, aux, dinv, N);
    scan_add2_k<<<gN, 256, 0, stream>>>(offs, aux, cnt, cursor, N, nb);
    scatter_dst_k<<<gM, 256, 0, stream>>>(srcp, dstp, cursor, src_sorted, E, N);

    // slice 0: h = x@W_lin + b -> project/pack chunk 0 (+V0)
    lin128_64_k<<<g16, 256, 0, stream>>>(x, W_lin, b_lin, hA, N);
    proj_qkv_k<true><<<gP, 192, 0, stream>>>(hA, Wq, bq, Wk, bk, Wv, bv, dinv,
                                             qb, PL, V0p, N, 0, RPB);

    // layer 1
    attn_g16_k<1, false><<<g16, 256, 0, stream>>>(offs, src_sorted, dinv, qb, PL, V0p,
                                                  nullptr, nullptr, outb, N);
    proj_qkv_k<false><<<gP, 192, 0, stream>>>(outb, Wq, bq, Wk, bk, Wv, bv, dinv,
                                              qb, PL, V0p, N, 1, RPB);
    // layer 2
    attn_g16_k<2, false><<<g16, 256, 0, stream>>>(offs, src_sorted, dinv, qb, PL, V0p,
                                                  nullptr, nullptr, outb, N);
    proj_qkv_k<false><<<gP, 192, 0, stream>>>(outb, Wq, bq, Wk, bk, Wv, bv, dinv,
                                              qb, PL, V0p, N, 2, RPB);
    // layer 3 + fused W_out -> d_out
    attn_g16_k<3, true><<<g16, 256, 0, stream>>>(offs, src_sorted, dinv, qb, PL, V0p,
                                                 W_out, b_out, out, N);
}

// Round 11
// 422.013 us; speedup vs baseline: 1.6391x; 1.0210x over previous
//
#include <hip/hip_runtime.h>

// ---------------------------------------------------------------------------
// DNANet round 11: wave-per-node attention, 4 edges/iteration (zero control
// divergence, 4x shorter dependent-gather chains) + fused W_out epilogue +
// register-stationary projections.
// N=50000, E=600000 (+N self loops), HID=64, HEADS=4, d=16.
//
// PL[node][l][dim] u32 = bf16(k_l) | bf16(v_l * dinv[node])<<16  (768 B/node)
// V0[node][dim]    u16 = bf16(v_0 * dinv[node])                  (128 B/node)
// q pre-scaled by 1/sqrt(d)=0.25.
//
// attn: one dst node per 64-lane wave. Lane = (edge-group eg = lane>>4,
// dim-quad gl = lane&15). Each iteration the 4 groups process 4 edges of the
// SAME node; per-group 4-lane shfl(1,2) head reduce; softmax; masked
// accumulate. End: shfl_xor(16,32) cross-group combine, one float4 write.
// ---------------------------------------------------------------------------

__device__ inline unsigned short bf16_rne(float f) {
    unsigned int u = __float_as_uint(f);
    unsigned int r = u + 0x7FFFu + ((u >> 16) & 1u);
    return (unsigned short)(r >> 16);
}
__device__ inline float kf(unsigned int u) { return __uint_as_float(u << 16); }
__device__ inline float vf(unsigned int u) { return __uint_as_float(u & 0xFFFF0000u); }

__global__ __launch_bounds__(256) void hist_dst_k(const int* __restrict__ dst,
                                                  int* __restrict__ cnt, int E) {
    int e = blockIdx.x * 256 + threadIdx.x;
    if (e < E) atomicAdd(&cnt[dst[e]], 1);
}

// Exclusive scan of (cnt[i]+1), stage 1 (1024-elem chunks); also emits dinv.
__global__ __launch_bounds__(256) void scan1_k(const int* __restrict__ cnt,
                                               int* __restrict__ excl,
                                               int* __restrict__ aux,
                                               float* __restrict__ dinv, int N) {
    __shared__ int wtot[4];
    int b = blockIdx.x, t = threadIdx.x;
    int lane = t & 63, w = t >> 6;
    int base = b * 1024 + t * 4;
    int v0 = (base + 0 < N) ? cnt[base + 0] + 1 : 0;
    int v1 = (base + 1 < N) ? cnt[base + 1] + 1 : 0;
    int v2 = (base + 2 < N) ? cnt[base + 2] + 1 : 0;
    int v3 = (base + 3 < N) ? cnt[base + 3] + 1 : 0;
    if (base + 0 < N) dinv[base + 0] = rsqrtf((float)v0);
    if (base + 1 < N) dinv[base + 1] = rsqrtf((float)v1);
    if (base + 2 < N) dinv[base + 2] = rsqrtf((float)v2);
    if (base + 3 < N) dinv[base + 3] = rsqrtf((float)v3);
    int s = v0 + v1 + v2 + v3;
    int incl = s;
#pragma unroll
    for (int off = 1; off < 64; off <<= 1) {
        int u = __shfl_up(incl, off);
        if (lane >= off) incl += u;
    }
    if (lane == 63) wtot[w] = incl;
    __syncthreads();
    int wb = 0;
#pragma unroll
    for (int j = 0; j < 4; ++j) if (j < w) wb += wtot[j];
    int ex = wb + incl - s;
    if (base + 0 < N) excl[base + 0] = ex;
    if (base + 1 < N) excl[base + 1] = ex + v0;
    if (base + 2 < N) excl[base + 2] = ex + v0 + v1;
    if (base + 3 < N) excl[base + 3] = ex + v0 + v1 + v2;
    if (t == 0) aux[b] = wtot[0] + wtot[1] + wtot[2] + wtot[3];
}

// Add chunk bases (self-computed wave-reduce over aux), mirror into cursor,
// and write offs[N] from the last element.
__global__ __launch_bounds__(256) void scan_add2_k(int* __restrict__ offs,
                                                   const int* __restrict__ aux,
                                                   const int* __restrict__ cnt,
                                                   int* __restrict__ cursor,
                                                   int N, int nb) {
    int i = blockIdx.x * 256 + threadIdx.x;
    int c = blockIdx.x >> 2;                  // 1024-chunk id (256*4 = 1024)
    int lane = threadIdx.x & 63;
    int v = (lane < c && lane < nb) ? aux[lane] : 0;
#pragma unroll
    for (int off = 32; off >= 1; off >>= 1) v += __shfl_xor(v, off);
    if (i < N) {
        int o = offs[i] + v;
        offs[i] = o;
        cursor[i] = o;
        if (i == N - 1) offs[N] = o + cnt[i] + 1;
    }
}

__global__ __launch_bounds__(256) void scatter_dst_k(const int* __restrict__ src,
                                                     const int* __restrict__ dst,
                                                     int* __restrict__ cursor,
                                                     int* __restrict__ src_sorted,
                                                     int E, int N) {
    int e = blockIdx.x * 256 + threadIdx.x;
    int M = E + N;
    if (e >= M) return;
    int s, d;
    if (e < E) { s = src[e]; d = dst[e]; }
    else       { s = d = e - E; }
    int pos = atomicAdd(&cursor[d], 1);
    src_sorted[pos] = s;
}

// h[N x 64] = x[N x 128] @ W[128 x 64] + b ; 16 rows/block (4 rows/thread).
__global__ __launch_bounds__(256) void lin128_64_k(const float* __restrict__ x,
                                                   const float* __restrict__ W,
                                                   const float* __restrict__ b,
                                                   float* __restrict__ y, int N) {
    __shared__ float sW[128 * 64];
    __shared__ float sb[64];
    for (int i = threadIdx.x; i < 128 * 64; i += 256) sW[i] = W[i];
    if (threadIdx.x < 64) sb[threadIdx.x] = b[threadIdx.x];
    __syncthreads();
    int w = threadIdx.x >> 6, c = threadIdx.x & 63;
    int r0 = blockIdx.x * 16 + w * 4;
    if (r0 >= N) return;
    const float* xr[4];
#pragma unroll
    for (int j = 0; j < 4; ++j) {
        int r = r0 + j; if (r > N - 1) r = N - 1;
        xr[j] = x + (size_t)r * 128;
    }
    float acc[4];
#pragma unroll
    for (int j = 0; j < 4; ++j) acc[j] = sb[c];
    for (int k = 0; k < 128; ++k) {
        float wv = sW[k * 64 + c];
#pragma unroll
        for (int j = 0; j < 4; ++j) acc[j] = fmaf(xr[j][k], wv, acc[j]);
    }
#pragma unroll
    for (int j = 0; j < 4; ++j) {
        int r = r0 + j;
        if (r < N) y[(size_t)r * 64 + c] = acc[j];
    }
}

// Projection: X (N x 64 fp32) -> q (x0.25), PL chunk l (bf16 k|v), V0 opt.
// Block = 192 threads = 3 waves (roles Q,K,V); lane holds W[:,c] in VGPRs;
// row elements broadcast via readlane. RPB rows per block.
template <bool WRITE_V0>
__global__ __launch_bounds__(192) void proj_qkv_k(const float* __restrict__ X,
                                                  const float* __restrict__ Wq, const float* __restrict__ bq,
                                                  const float* __restrict__ Wk, const float* __restrict__ bk,
                                                  const float* __restrict__ Wv, const float* __restrict__ bv,
                                                  const float* __restrict__ dinv,
                                                  float* __restrict__ q,
                                                  unsigned int* __restrict__ PL,
                                                  unsigned short* __restrict__ V0,
                                                  int N, int l, int RPB) {
    int w = threadIdx.x >> 6;    // role: 0=Q 1=K 2=V
    int c = threadIdx.x & 63;
    const float* W = (w == 0) ? Wq : (w == 1) ? Wk : Wv;
    const float* B = (w == 0) ? bq : (w == 1) ? bk : bv;
    float wr[64];
#pragma unroll
    for (int k = 0; k < 64; ++k) wr[k] = W[k * 64 + c];
    float bias = B[c];
    int r0 = blockIdx.x * RPB;
    int r1 = r0 + RPB; if (r1 > N) r1 = N;
    unsigned short* PLh = (unsigned short*)PL;
    for (int r = r0; r < r1; ++r) {
        float xv = X[(size_t)r * 64 + c];
        float a = bias;
#pragma unroll
        for (int k = 0; k < 64; ++k) {
            float xk = __int_as_float(__builtin_amdgcn_readlane(__float_as_int(xv), k));
            a = fmaf(xk, wr[k], a);
        }
        if (w == 0) {
            q[(size_t)r * 64 + c] = a * 0.25f;           // fold 1/sqrt(16)
        } else if (w == 1) {
            PLh[((size_t)r * 192 + l * 64 + c) * 2] = bf16_rne(a);
        } else {
            unsigned short vb = bf16_rne(a * dinv[r]);
            PLh[((size_t)r * 192 + l * 64 + c) * 2 + 1] = vb;
            if (WRITE_V0) V0[(size_t)r * 64 + c] = vb;
        }
    }
}

// Wave-per-node attention: 4 edges/iteration, depth-2 prefetch, no divergence.
// EMIT_OUT: fused W_out epilogue (4 nodes/block).
template <int L, bool EMIT_OUT>
__global__ __launch_bounds__(256) void attn_w64_k(const int* __restrict__ offs,
                                                  const int* __restrict__ src_sorted,
                                                  const float* __restrict__ dinv,
                                                  const float* __restrict__ q,
                                                  const unsigned int* __restrict__ PL,
                                                  const unsigned short* __restrict__ V0,
                                                  const float* __restrict__ Wo,
                                                  const float* __restrict__ bo,
                                                  float* __restrict__ outv,   // rows (Nx64) or final (Nx16)
                                                  int N) {
    constexpr int LDSN = EMIT_OUT ? (4 * 68 + 64 * 16 + 16) : 1;
    __shared__ float lds[LDSN];
    float* rowS = lds;                    // [4][68]
    float* sWo  = lds + 4 * 68;           // [64][16]
    float* sbo  = sWo + 64 * 16;          // [16]
    if (EMIT_OUT) {
        for (int i = threadIdx.x; i < 64 * 16; i += 256) sWo[i] = Wo[i];
        if (threadIdx.x < 16) sbo[threadIdx.x] = bo[threadIdx.x];
    }

    int wv   = threadIdx.x >> 6;          // wave id in block (node slot)
    int lane = threadIdx.x & 63;
    int gl   = lane & 15;                 // dim-quad
    int eg   = lane >> 4;                 // edge-group 0..3
    int d    = blockIdx.x * 4 + wv;

    float a0 = 0.f, a1 = 0.f, a2 = 0.f, a3 = 0.f;

    if (d < N) {
        int beg = offs[d], end = offs[d + 1];
        float4 qv = make_float4(0.f, 0.f, 0.f, 0.f);
        if (L > 1) qv = *(const float4*)(q + (size_t)d * 64 + gl * 4);

        for (int base = beg; base < end; base += 64) {
            int m = end - base;
            if (m > 64) m = 64;
            int sid = (base + lane < end) ? src_sorted[base + lane] : 0;
            int nit = (m + 3) >> 2;
            int mm1 = m - 1;

            // prefetch iteration 0
            int idx = eg; if (idx > mm1) idx = mm1;
            int sA = __shfl(sid, idx);
            uint4 A0, A1, A2, B0, B1, B2;
            uint2 Av, Bv;
            if (L == 1) {
                Av = *(const uint2*)(V0 + (size_t)sA * 64 + gl * 4);
            } else {
                const uint4* pa = (const uint4*)(PL + (size_t)sA * 192) + gl;
                A0 = pa[0]; A1 = pa[16]; if (L > 2) A2 = pa[32];
            }

            for (int i = 0; i < nit; ++i) {
                int nidx = (i + 1) * 4 + eg; if (nidx > mm1) nidx = mm1;
                int sB = __shfl(sid, nidx);
                if (L == 1) {
                    Bv = *(const uint2*)(V0 + (size_t)sB * 64 + gl * 4);
                } else {
                    const uint4* pb = (const uint4*)(PL + (size_t)sB * 192) + gl;
                    B0 = pb[0]; B1 = pb[16]; if (L > 2) B2 = pb[32];
                }

                float vm = ((i * 4 + eg) <= mm1) ? 1.f : 0.f;
                if (L == 1) {
                    a0 += vm * kf(Av.x); a1 += vm * vf(Av.x);
                    a2 += vm * kf(Av.y); a3 += vm * vf(Av.y);
                } else {
                    float p0 = qv.x * kf(A0.x);
                    p0 = fmaf(qv.y, kf(A0.y), p0);
                    p0 = fmaf(qv.z, kf(A0.z), p0);
                    p0 = fmaf(qv.w, kf(A0.w), p0);
                    float p1 = qv.x * kf(A1.x);
                    p1 = fmaf(qv.y, kf(A1.y), p1);
                    p1 = fmaf(qv.z, kf(A1.z), p1);
                    p1 = fmaf(qv.w, kf(A1.w), p1);
                    float p2 = 0.f;
                    if (L > 2) {
                        p2 = qv.x * kf(A2.x);
                        p2 = fmaf(qv.y, kf(A2.y), p2);
                        p2 = fmaf(qv.z, kf(A2.z), p2);
                        p2 = fmaf(qv.w, kf(A2.w), p2);
                    }
                    // head reduce within 4-lane cluster (stays inside group)
                    p0 += __shfl_xor(p0, 1); p0 += __shfl_xor(p0, 2);
                    p1 += __shfl_xor(p1, 1); p1 += __shfl_xor(p1, 2);
                    if (L > 2) { p2 += __shfl_xor(p2, 1); p2 += __shfl_xor(p2, 2); }
                    float w0, w1, w2 = 0.f;
                    if (L == 2) {
                        float e = __expf(p1 - p0);
                        w0 = __builtin_amdgcn_rcpf(1.0f + e);
                        w1 = 1.0f - w0;
                    } else {
                        float mx = fmaxf(fmaxf(p0, p1), p2);
                        float e0 = __expf(p0 - mx);
                        float e1 = __expf(p1 - mx);
                        float e2 = __expf(p2 - mx);
                        float inv = __builtin_amdgcn_rcpf(e0 + e1 + e2);
                        w0 = e0 * inv; w1 = e1 * inv; w2 = e2 * inv;
                    }
                    w0 *= vm; w1 *= vm; if (L > 2) w2 *= vm;
                    a0 = fmaf(w0, vf(A0.x), a0);
                    a1 = fmaf(w0, vf(A0.y), a1);
                    a2 = fmaf(w0, vf(A0.z), a2);
                    a3 = fmaf(w0, vf(A0.w), a3);
                    a0 = fmaf(w1, vf(A1.x), a0);
                    a1 = fmaf(w1, vf(A1.y), a1);
                    a2 = fmaf(w1, vf(A1.z), a2);
                    a3 = fmaf(w1, vf(A1.w), a3);
                    if (L > 2) {
                        a0 = fmaf(w2, vf(A2.x), a0);
                        a1 = fmaf(w2, vf(A2.y), a1);
                        a2 = fmaf(w2, vf(A2.z), a2);
                        a3 = fmaf(w2, vf(A2.w), a3);
                    }
                }
                if (L == 1) {
                    Av = Bv;
                } else {
                    A0 = B0; A1 = B1;
                    if (L > 2) A2 = B2;
                }
            }
        }

        // cross-group combine (4 partial sums -> total in every lane)
        a0 += __shfl_xor(a0, 16); a0 += __shfl_xor(a0, 32);
        a1 += __shfl_xor(a1, 16); a1 += __shfl_xor(a1, 32);
        a2 += __shfl_xor(a2, 16); a2 += __shfl_xor(a2, 32);
        a3 += __shfl_xor(a3, 16); a3 += __shfl_xor(a3, 32);
        float dv = dinv[d];
        a0 *= dv; a1 *= dv; a2 *= dv; a3 *= dv;
    }

    if (EMIT_OUT) {
        if (d < N && eg == 0) {
            rowS[wv * 68 + gl * 4 + 0] = a0;
            rowS[wv * 68 + gl * 4 + 1] = a1;
            rowS[wv * 68 + gl * 4 + 2] = a2;
            rowS[wv * 68 + gl * 4 + 3] = a3;
        }
        __syncthreads();
        if (threadIdx.x < 64) {
            int node = threadIdx.x >> 4;
            int co   = threadIdx.x & 15;
            int dn   = blockIdx.x * 4 + node;
            if (dn < N) {
                float acc = sbo[co];
#pragma unroll 16
                for (int k = 0; k < 64; ++k)
                    acc = fmaf(rowS[node * 68 + k], sWo[k * 16 + co], acc);
                outv[(size_t)dn * 16 + co] = acc;
            }
        }
    } else {
        if (d < N && eg == 0)
            *(float4*)(outv + (size_t)d * 64 + gl * 4) =
                make_float4(a0, a1, a2, a3);
    }
}

extern "C" void kernel_launch(void* const* d_in, const int* in_sizes, int n_in,
                              void* d_out, int out_size, void* d_ws, size_t ws_size,
                              hipStream_t stream) {
    const float* x     = (const float*)d_in[0];
    const int*   ei    = (const int*)d_in[1];
    const float* W_lin = (const float*)d_in[2];
    const float* b_lin = (const float*)d_in[3];
    const float* Wq    = (const float*)d_in[4];
    const float* bq    = (const float*)d_in[5];
    const float* Wk    = (const float*)d_in[6];
    const float* bk    = (const float*)d_in[7];
    const float* Wv    = (const float*)d_in[8];
    const float* bv    = (const float*)d_in[9];
    const float* W_out = (const float*)d_in[10];
    const float* b_out = (const float*)d_in[11];
    float* out = (float*)d_out;

    const int N = in_sizes[0] / 128;
    const int E = in_sizes[1] / 2;
    const int M = E + N;
    const int* srcp = ei;
    const int* dstp = ei + E;

    char* wsb = (char*)d_ws;
    float*          dinv       = (float*)wsb;           wsb += (size_t)N * sizeof(float);
    int*            cnt        = (int*)wsb;             wsb += (size_t)N * sizeof(int);
    int*            offs       = (int*)wsb;             wsb += (size_t)(N + 1) * sizeof(int);
    int*            cursor     = (int*)wsb;             wsb += (size_t)N * sizeof(int);
    int*            aux        = (int*)wsb;             wsb += 64 * sizeof(int);
    int*            src_sorted = (int*)wsb;             wsb += (size_t)M * sizeof(int);
    float*          qb         = (float*)wsb;           wsb += (size_t)N * 64 * sizeof(float);
    unsigned int*   PL         = (unsigned int*)wsb;    wsb += (size_t)N * 192 * sizeof(unsigned int);
    unsigned short* V0p        = (unsigned short*)wsb;  wsb += (size_t)N * 64 * sizeof(unsigned short);
    float*          hA         = (float*)wsb;           wsb += (size_t)N * 64 * sizeof(float);
    float*          outb       = (float*)wsb;

    const int gN   = (N + 255) / 256;
    const int gE   = (E + 255) / 256;
    const int gM   = (M + 255) / 256;
    const int g16  = (N + 15) / 16;
    const int gA4  = (N + 3) / 4;          // attn: 4 nodes (waves) per block
    const int nb   = (N + 1023) / 1024;
    const int RPB  = 16;
    const int gP   = (N + RPB - 1) / RPB;

    // degree -> dinv + dst-CSR
    hipMemsetAsync(cnt, 0, (size_t)N * sizeof(int), stream);
    hist_dst_k<<<gE, 256, 0, stream>>>(dstp, cnt, E);
    scan1_k<<<nb, 256, 0, stream>>>(cnt, offs, aux, dinv, N);
    scan_add2_k<<<gN, 256, 0, stream>>>(offs, aux, cnt, cursor, N, nb);
    scatter_dst_k<<<gM, 256, 0, stream>>>(srcp, dstp, cursor, src_sorted, E, N);

    // slice 0: h = x@W_lin + b -> project/pack chunk 0 (+V0)
    lin128_64_k<<<g16, 256, 0, stream>>>(x, W_lin, b_lin, hA, N);
    proj_qkv_k<true><<<gP, 192, 0, stream>>>(hA, Wq, bq, Wk, bk, Wv, bv, dinv,
                                             qb, PL, V0p, N, 0, RPB);

    // layer 1
    attn_w64_k<1, false><<<gA4, 256, 0, stream>>>(offs, src_sorted, dinv, qb, PL, V0p,
                                                  nullptr, nullptr, outb, N);
    proj_qkv_k<false><<<gP, 192, 0, stream>>>(outb, Wq, bq, Wk, bk, Wv, bv, dinv,
                                              qb, PL, V0p, N, 1, RPB);
    // layer 2
    attn_w64_k<2, false><<<gA4, 256, 0, stream>>>(offs, src_sorted, dinv, qb, PL, V0p,
                                                  nullptr, nullptr, outb, N);
    proj_qkv_k<false><<<gP, 192, 0, stream>>>(outb, Wq, bq, Wk, bk, Wv, bv, dinv,
                                              qb, PL, V0p, N, 2, RPB);
    // layer 3 + fused W_out -> d_out
    attn_w64_k<3, true><<<gA4, 256, 0, stream>>>(offs, src_sorted, dinv, qb, PL, V0p,
                                                 W_out, b_out, out, N);
}